// Round 7
// baseline (406.810 us; speedup 1.0000x reference)
//
#include <hip/hip_runtime.h>

// TreeLRU: B=16, N=4095 heap, IN=OUT=512, S=256.
// Round 11: GEMM ported to the 256^2 8-phase counted-vmcnt template (T3+T4+T5):
// BM=BN=256, BK=64, 512 thr (8 waves x [256 rows x 32 cols]), LDS 128KB dbuf.
// Per K-step 4 phases: {12 ds_read (A quadrant p + own B) | stage 1 half-tile
// of step s+1 | s_barrier | setprio + 16 MFMA + setprio | s_barrier}.
// Stage order B0,B1,A0,A1; entry vmcnt(2) (A1 of this step still in flight,
// consumed at phase 2), phase-1-tail vmcnt(4). vmcnt never 0 in main loop.
// Waits precede barriers so barriers publish all waves' global_load_lds DMA.
// LDS chunk-XOR slot=kc^(row&7) (0 conflicts, proven r5-r10), linear DMA dest.
// gemm1 A-f32 fusion REVERTED (135us vs 85+cvt); prep_all = round-5 version.

#define ROWS 65520
#define KDIM 512

typedef __attribute__((ext_vector_type(8))) short bf16x8;
typedef __attribute__((ext_vector_type(4))) float f32x4;

__device__ __forceinline__ unsigned short f2bf(float f) {
    unsigned int u = __float_as_uint(f);
    unsigned int r = (u + 0x7FFFu + ((u >> 16) & 1u)) >> 16;
    return (unsigned short)r;
}
__device__ __forceinline__ float b2f(unsigned short h) {
    return __uint_as_float(((unsigned int)h) << 16);
}
__device__ __forceinline__ float b2f_lo(unsigned int p) {
    return __uint_as_float(p << 16);
}
__device__ __forceinline__ float b2f_hi(unsigned int p) {
    return __uint_as_float(p & 0xFFFF0000u);
}

// ---------------- merged prep: prep_M | prep_C | prep_bias | cvt ----------------
#define PC_BASE   1024
#define PB_BASE   2048
#define CVT_BASE  2176
#define CVT_BLKS  2048
#define PREP_GRID 4224
#define CVT_N4    8386560          // ROWS*512/4
#define CVT_STR   (CVT_BLKS * 256) // 524288

__global__ __launch_bounds__(256) void prep_all(const float* __restrict__ x,
                                                unsigned short* __restrict__ x16,
                                                const float* __restrict__ W,
                                                const float* __restrict__ Bre,
                                                const float* __restrict__ Bim,
                                                const float* __restrict__ gamma_log,
                                                unsigned short* __restrict__ M16,
                                                const float* __restrict__ bin,
                                                float* __restrict__ biasc,
                                                const float* __restrict__ Cre,
                                                const float* __restrict__ Cim,
                                                unsigned short* __restrict__ C16) {
    __shared__ float Bs[16][17];
    __shared__ float Ws[16][17];
    const int blk = blockIdx.x;
    const int t = threadIdx.x;

    if (blk < PC_BASE) {
        // ---- prep_M: 32x32 grid of 16x16 tiles ----
        const int bx = blk & 31;
        const int by = blk >> 5;
        const int tx = t & 15;
        const int ty = t >> 4;
        const int j  = bx * 16 + tx;
        const int cc = by * 16 + ty;
        const float* Bsel = (cc < 256) ? (Bre + (size_t)cc * 512)
                                       : (Bim + (size_t)(cc - 256) * 512);
        float acc = 0.f;
        for (int kt = 0; kt < 512; kt += 16) {
            Bs[ty][tx] = Bsel[kt + tx];
            Ws[ty][tx] = W[(size_t)(kt + ty) * 512 + j];
            __syncthreads();
#pragma unroll
            for (int k = 0; k < 16; ++k) acc += Bs[ty][k] * Ws[k][tx];
            __syncthreads();
        }
        float g = expf(gamma_log[cc & 255]);
        M16[(size_t)cc * 512 + j] = f2bf(acc * g);
    } else if (blk < PB_BASE) {
        // ---- prep_C ----
        int idx = (blk - PC_BASE) * 256 + t;
        int o = idx >> 9;
        int s = idx & 511;
        float v = (s < 256) ? Cre[(size_t)o * 256 + s] : -Cim[(size_t)o * 256 + (s - 256)];
        C16[idx] = f2bf(v);
    } else if (blk < CVT_BASE) {
        // ---- prep_bias ----
        const int c = (blk - PB_BASE) * 4 + (t >> 6);
        const int lane = t & 63;
        const float* Bsel = (c < 256) ? (Bre + (size_t)c * 512)
                                      : (Bim + (size_t)(c - 256) * 512);
        float acc = 0.f;
#pragma unroll
        for (int i = lane; i < 512; i += 64) acc += bin[i] * Bsel[i];
#pragma unroll
        for (int off = 32; off > 0; off >>= 1) acc += __shfl_down(acc, off, 64);
        if (lane == 0) biasc[c] = acc * expf(gamma_log[c & 255]);
    } else {
        // ---- cvt f32 -> bf16: 16 loads in flight, then 16 cvt+stores ----
        const int i = (blk - CVT_BASE) * 256 + t;
        const float4* src = (const float4*)x;
        ushort4* dst = (ushort4*)x16;
        if (i < CVT_N4 - 15 * CVT_STR) {
            float4 v0  = src[i];
            float4 v1  = src[i +  1 * CVT_STR];
            float4 v2  = src[i +  2 * CVT_STR];
            float4 v3  = src[i +  3 * CVT_STR];
            float4 v4  = src[i +  4 * CVT_STR];
            float4 v5  = src[i +  5 * CVT_STR];
            float4 v6  = src[i +  6 * CVT_STR];
            float4 v7  = src[i +  7 * CVT_STR];
            float4 v8  = src[i +  8 * CVT_STR];
            float4 v9  = src[i +  9 * CVT_STR];
            float4 v10 = src[i + 10 * CVT_STR];
            float4 v11 = src[i + 11 * CVT_STR];
            float4 v12 = src[i + 12 * CVT_STR];
            float4 v13 = src[i + 13 * CVT_STR];
            float4 v14 = src[i + 14 * CVT_STR];
            float4 v15 = src[i + 15 * CVT_STR];
#define CVT1(K, V)                                                             \
            { ushort4 o; o.x = f2bf(V.x); o.y = f2bf(V.y);                     \
              o.z = f2bf(V.z); o.w = f2bf(V.w); dst[i + (K) * CVT_STR] = o; }
            CVT1(0, v0)  CVT1(1, v1)  CVT1(2, v2)  CVT1(3, v3)
            CVT1(4, v4)  CVT1(5, v5)  CVT1(6, v6)  CVT1(7, v7)
            CVT1(8, v8)  CVT1(9, v9)  CVT1(10, v10) CVT1(11, v11)
            CVT1(12, v12) CVT1(13, v13) CVT1(14, v14) CVT1(15, v15)
#undef CVT1
        } else {
#pragma unroll
            for (int k = 0; k < 16; ++k) {
                int idx = i + k * CVT_STR;
                if (idx < CVT_N4) {
                    float4 v = src[idx];
                    ushort4 o;
                    o.x = f2bf(v.x); o.y = f2bf(v.y); o.z = f2bf(v.z); o.w = f2bf(v.w);
                    dst[idx] = o;
                }
            }
        }
    }
}

// ---------------- 8-phase 256x256 bf16 GEMM: C = A @ B^T (+bias) ----------------
// Grid 512 x 512thr. Block: xcd=bid&7, lid=bid>>3; rt=xcd*32+(lid>>1), ct=lid&1
// (col-tile siblings of a row-tile are same-XCD -> A panel L2-shared).
// 8 waves, wave w owns rows [0,256) x cols [w*32, w*32+32): acc[16][2] f32x4.
// K: 8 steps of BK=64, dbuf. Step s, 4 phases; phase p reads A rows
// [p*64,p*64+64) (half p>>1) + own B cols; stages half-tiles of step s+1 in
// order B0(p0) B1(p1) A0(p2) A1(p3), 2 global_load_lds each.
// Waits (per-thread VMEM program order, 8 loads/step): entry vmcnt(2)
// [A1(s) may fly until phase 2]; phase-1 tail vmcnt(4) [A1(s) landed,
// B0/B1(s+1) in flight]. Step 7: no stages; phase-1 tail vmcnt(0) (tail only).
// All barriers are asm s_barrier with "memory" clobber (publish DMA; prevent
// IR hoisting of LDS reads across wait points).
template <bool OUT_BF16>
__global__ __launch_bounds__(512, 2) void gemm_mfma(const unsigned short* __restrict__ A,
                                                    const unsigned short* __restrict__ Bm,
                                                    const float* __restrict__ bias,
                                                    void* __restrict__ Cout,
                                                    int Mrows) {
    __shared__ __align__(16) unsigned short As[2][16384];   // [buf][256 rows x 64 k]
    __shared__ __align__(16) unsigned short Bs[2][16384];
    const int t = threadIdx.x;          // 0..511
    const int lane = t & 63;
    const int wn = t >> 6;              // wave 0..7: cols wn*32..+32
    const int bid = blockIdx.x;
    const int xcd = bid & 7;
    const int lid = bid >> 3;           // 0..63
    const int rt = xcd * 32 + (lid >> 1);
    const int ct = lid & 1;
    const int row0 = rt * 256;
    const int col0 = ct * 256;

    // stage geometry: half h (rows h*128..+128), q in {0,1}: chunk c2=q*512+t
    const unsigned short* gA[2][2];
    const unsigned short* gB[2][2];
#pragma unroll
    for (int h = 0; h < 2; ++h) {
#pragma unroll
        for (int q = 0; q < 2; ++q) {
            int c2  = q * 512 + t;      // 0..1023
            int row = c2 >> 3;          // 0..127
            int kc  = c2 & 7;
            int lrow = h * 128 + row;
            int kg  = kc ^ (lrow & 7);  // source-permuted k-chunk
            int ar  = row0 + lrow; if (ar >= Mrows) ar = Mrows - 1;
            gA[h][q] = A + (size_t)ar * KDIM + kg * 8;
            gB[h][q] = Bm + (size_t)(col0 + lrow) * KDIM + kg * 8;
        }
    }

#define STG_A(BUF, H, KT)                                                      \
    do {                                                                       \
        _Pragma("unroll")                                                      \
        for (int q = 0; q < 2; ++q)                                            \
            __builtin_amdgcn_global_load_lds(                                  \
                (const __attribute__((address_space(1))) unsigned int*)(gA[H][q] + (KT)), \
                (__attribute__((address_space(3))) unsigned int*)(&As[BUF][(H) * 8192 + (q * 512 + t) * 8]), \
                16, 0, 0);                                                     \
    } while (0)
#define STG_B(BUF, H, KT)                                                      \
    do {                                                                       \
        _Pragma("unroll")                                                      \
        for (int q = 0; q < 2; ++q)                                            \
            __builtin_amdgcn_global_load_lds(                                  \
                (const __attribute__((address_space(1))) unsigned int*)(gB[H][q] + (KT)), \
                (__attribute__((address_space(3))) unsigned int*)(&Bs[BUF][(H) * 8192 + (q * 512 + t) * 8]), \
                16, 0, 0);                                                     \
    } while (0)
#define BARRIER() asm volatile("s_barrier" ::: "memory")

    f32x4 acc[16][2] = {};

    // kt for step s (rotated by row-tile to spread HBM k-phase; ct-siblings aligned)
#define KTOF(S) ((((rt & 7) + (S)) & 7) * 64)

    // prologue: step 0, order B0,B1,A0,A1  -> 8 loads outstanding
    {
        const int kt = KTOF(0);
        STG_B(0, 0, kt); STG_B(0, 1, kt); STG_A(0, 0, kt); STG_A(0, 1, kt);
    }

    for (int s = 0; s < 8; ++s) {
        const int cur = s & 1;
        const int nkt = KTOF(s + 1);
        // entry: B0,B1,A0 of step s resident; A1 (2 newest) may fly
        asm volatile("s_waitcnt vmcnt(2)" ::: "memory");
        BARRIER();
#pragma unroll
        for (int p = 0; p < 4; ++p) {
            // ds_read quadrant p from buf[cur]
            bf16x8 af[4][2], bfr[2][2];
#pragma unroll
            for (int i = 0; i < 4; ++i) {
                int row = p * 64 + i * 16 + (lane & 15);
#pragma unroll
                for (int kk = 0; kk < 2; ++kk) {
                    int kca = (kk * 4 + (lane >> 4)) ^ (row & 7);
                    af[i][kk] = *(const bf16x8*)(&As[cur][row * 64 + kca * 8]);
                }
            }
#pragma unroll
            for (int j = 0; j < 2; ++j) {
                int colr = wn * 32 + j * 16 + (lane & 15);
#pragma unroll
                for (int kk = 0; kk < 2; ++kk) {
                    int kcb = (kk * 4 + (lane >> 4)) ^ (colr & 7);
                    bfr[j][kk] = *(const bf16x8*)(&Bs[cur][colr * 64 + kcb * 8]);
                }
            }
            // stage one half-tile of step s+1 into buf[cur^1]
            if (s < 7) {
                if (p == 0)      STG_B(cur ^ 1, 0, nkt);
                else if (p == 1) STG_B(cur ^ 1, 1, nkt);
                else if (p == 2) STG_A(cur ^ 1, 0, nkt);
                else             STG_A(cur ^ 1, 1, nkt);
            }
            BARRIER();                       // align phase roles across waves
            __builtin_amdgcn_s_setprio(1);
#pragma unroll
            for (int i = 0; i < 4; ++i)
#pragma unroll
                for (int j = 0; j < 2; ++j)
#pragma unroll
                    for (int kk = 0; kk < 2; ++kk)
                        acc[p * 4 + i][j] = __builtin_amdgcn_mfma_f32_16x16x32_bf16(
                            af[i][kk], bfr[j][kk], acc[p * 4 + i][j], 0, 0, 0);
            __builtin_amdgcn_s_setprio(0);
            if (p == 1) {
                // before phase 2 reads A rows 128..255: own A1(s) must land;
                // B0/B1(s+1) (4 loads) stay in flight. Step 7: tail drain.
                if (s < 7) asm volatile("s_waitcnt vmcnt(4)" ::: "memory");
                else       asm volatile("s_waitcnt vmcnt(0)" ::: "memory");
            }
            BARRIER();                       // publishes waited DMA to all waves
        }
    }
#undef KTOF
#undef BARRIER
#undef STG_B
#undef STG_A

    // epilogue: C/D layout col=lane&15, row=(lane>>4)*4+reg [m89/m91]
    const int cq = lane >> 4;
    const int cl = lane & 15;
#pragma unroll
    for (int I = 0; I < 16; ++I) {
#pragma unroll
        for (int j = 0; j < 2; ++j) {
#pragma unroll
            for (int r = 0; r < 4; ++r) {
                int grow = row0 + I * 16 + cq * 4 + r;
                int gcol = col0 + wn * 32 + j * 16 + cl;
                if (grow < Mrows) {
                    float v = acc[I][j][r];
                    if (bias) v += bias[gcol];
                    if (OUT_BF16)
                        ((unsigned short*)Cout)[(size_t)grow * 512 + gcol] = f2bf(v);
                    else
                        ((float*)Cout)[(size_t)grow * 512 + gcol] = v;
                }
            }
        }
    }
}

// ---------------- tree recurrence, v2 (unchanged) ----------------
template <int E>
__global__ __launch_bounds__(256) void tree_up2(unsigned short* __restrict__ buf,
                                                const float* __restrict__ nu_log,
                                                const float* __restrict__ theta_log,
                                                int root_base, int nroots) {
    const int b = blockIdx.x;
    const int h = threadIdx.x >> 7;
    const int j2 = (threadIdx.x & 127) * 2;
    const int rr = blockIdx.y * 2 + h;
    if (rr >= nroots) return;
    const int rs = root_base + rr;
    constexpr int LEAVES = 1 << E;
    constexpr int NODES = LEAVES - 1;

    float lr0, li0, lr1, li1;
    { const float lam = expf(-expf(nu_log[j2]));     const float th = expf(theta_log[j2]);
      lr0 = lam * cosf(th); li0 = lam * sinf(th); }
    { const float lam = expf(-expf(nu_log[j2 + 1])); const float th = expf(theta_log[j2 + 1]);
      lr1 = lam * cosf(th); li1 = lam * sinf(th); }
    const size_t base = (size_t)b * 4095;

    unsigned int pr[LEAVES], pi[LEAVES];
    const int nbL = ((rs + 1) << E) - 1;
#pragma unroll
    for (int i = 0; i < LEAVES; ++i) {
        const size_t r = (base + nbL + i) * 512;
        pr[i] = *(const unsigned int*)(buf + r + j2);
        pi[i] = *(const unsigned int*)(buf + r + 256 + j2);
    }
    unsigned int qr[NODES], qi[NODES];
#pragma unroll
    for (int e = E - 1; e >= 0; --e) {
#pragma unroll
        for (int i = 0; i < (1 << e); ++i) {
            const int idx = LEAVES - (2 << e) + i;
            const size_t r = (base + (((rs + 1) << e) - 1) + i) * 512;
            qr[idx] = *(const unsigned int*)(buf + r + j2);
            qi[idx] = *(const unsigned int*)(buf + r + 256 + j2);
        }
    }
    __builtin_amdgcn_sched_barrier(0);

    float vr0[LEAVES], vi0[LEAVES], vr1[LEAVES], vi1[LEAVES];
#pragma unroll
    for (int i = 0; i < LEAVES; ++i) {
        vr0[i] = b2f_lo(pr[i]); vr1[i] = b2f_hi(pr[i]);
        vi0[i] = b2f_lo(pi[i]); vi1[i] = b2f_hi(pi[i]);
    }
#pragma unroll
    for (int e = E - 1; e >= 0; --e) {
#pragma unroll
        for (int i = 0; i < (1 << e); ++i) {
            const int idx = LEAVES - (2 << e) + i;
            const float cr0 = vr0[2 * i] + vr0[2 * i + 1];
            const float ci0 = vi0[2 * i] + vi0[2 * i + 1];
            const float cr1 = vr1[2 * i] + vr1[2 * i + 1];
            const float ci1 = vi1[2 * i] + vi1[2 * i + 1];
            const float hr0 = lr0 * cr0 - li0 * ci0 + b2f_lo(qr[idx]);
            const float hi0 = lr0 * ci0 + li0 * cr0 + b2f_lo(qi[idx]);
            const float hr1 = lr1 * cr1 - li1 * ci1 + b2f_hi(qr[idx]);
            const float hi1 = lr1 * ci1 + li1 * cr1 + b2f_hi(qi[idx]);
            const size_t r = (base + (((rs + 1) << e) - 1) + i) * 512;
            *(unsigned int*)(buf + r + j2) =
                (unsigned int)f2bf(hr0) | ((unsigned int)f2bf(hr1) << 16);
            *(unsigned int*)(buf + r + 256 + j2) =
                (unsigned int)f2bf(hi0) | ((unsigned int)f2bf(hi1) << 16);
            vr0[i] = hr0; vi0[i] = hi0; vr1[i] = hr1; vi1[i] = hi1;
        }
    }
}

extern "C" void kernel_launch(void* const* d_in, const int* in_sizes, int n_in,
                              void* d_out, int out_size, void* d_ws, size_t ws_size,
                              hipStream_t stream) {
    const float* x         = (const float*)d_in[0];
    const float* W_in      = (const float*)d_in[2];
    const float* b_in      = (const float*)d_in[3];
    const float* nu_log    = (const float*)d_in[4];
    const float* theta_log = (const float*)d_in[5];
    const float* gamma_log = (const float*)d_in[6];
    const float* B_re      = (const float*)d_in[7];
    const float* B_im      = (const float*)d_in[8];
    const float* C_re      = (const float*)d_in[9];
    const float* C_im      = (const float*)d_in[10];
    float* out = (float*)d_out;

    char* ws = (char*)d_ws;
    const size_t HB = (size_t)ROWS * 512 * 2;   // 67,092,480 bytes
    unsigned short* x16   = (unsigned short*)ws;
    unsigned short* hb16  = (unsigned short*)(ws + HB);
    unsigned short* M16   = (unsigned short*)(ws + 2 * HB);
    unsigned short* C16   = (unsigned short*)(ws + 2 * HB + 512 * 512 * 2);
    float*          biasc = (float*)(ws + 2 * HB + 2 * 512 * 512 * 2);

    prep_all<<<PREP_GRID, 256, 0, stream>>>(x, x16, W_in, B_re, B_im, gamma_log,
                                            M16, b_in, biasc, C_re, C_im, C16);

    gemm_mfma<true><<<512, 512, 0, stream>>>(x16, M16, biasc, hb16, ROWS);

    tree_up2<4><<<dim3(16, 64), 256, 0, stream>>>(hb16, nu_log, theta_log, 127, 128);
    tree_up2<4><<<dim3(16, 4),  256, 0, stream>>>(hb16, nu_log, theta_log, 7, 8);
    tree_up2<3><<<dim3(16, 1),  256, 0, stream>>>(hb16, nu_log, theta_log, 0, 1);

    gemm_mfma<false><<<512, 512, 0, stream>>>(hb16, C16, nullptr, out, ROWS);
}

// Round 8
// 373.513 us; speedup vs baseline: 1.0891x; 1.0891x over previous
//
#include <hip/hip_runtime.h>

// TreeLRU: B=16, N=4095 heap, IN=OUT=512, S=256.
// Round 12: (1) GEMM occupancy test, finally un-confounded: round-9 BK=32
// inner loop (proven correct, 0 bank conflicts), 32KB LDS, NON-persistent
// 2048-block grid, __launch_bounds__(256,4) -> 4 blocks/CU (16 waves/CU).
// Every prior config was 8 waves/CU (occupancy ~20%) regardless of schedule;
// 2-phase and 8-phase both landed at ~84-86us => schedule-invariant stall,
// TLP is the untested lever. (2) cvt: VGPR=36 proved the compiler sank the
// 16 loads (again); sched_barrier(0) between load and store blocks pins
// them (same recipe that fixed tree_up2).

#define ROWS 65520
#define KDIM 512

typedef __attribute__((ext_vector_type(8))) short bf16x8;
typedef __attribute__((ext_vector_type(4))) float f32x4;

__device__ __forceinline__ unsigned short f2bf(float f) {
    unsigned int u = __float_as_uint(f);
    unsigned int r = (u + 0x7FFFu + ((u >> 16) & 1u)) >> 16;
    return (unsigned short)r;
}
__device__ __forceinline__ float b2f(unsigned short h) {
    return __uint_as_float(((unsigned int)h) << 16);
}
__device__ __forceinline__ float b2f_lo(unsigned int p) {
    return __uint_as_float(p << 16);
}
__device__ __forceinline__ float b2f_hi(unsigned int p) {
    return __uint_as_float(p & 0xFFFF0000u);
}

// ---------------- merged prep: prep_M | prep_C | prep_bias | cvt ----------------
#define PC_BASE   1024
#define PB_BASE   2048
#define CVT_BASE  2176
#define CVT_BLKS  2048
#define PREP_GRID 4224
#define CVT_N4    8386560          // ROWS*512/4
#define CVT_STR   (CVT_BLKS * 256) // 524288

__global__ __launch_bounds__(256) void prep_all(const float* __restrict__ x,
                                                unsigned short* __restrict__ x16,
                                                const float* __restrict__ W,
                                                const float* __restrict__ Bre,
                                                const float* __restrict__ Bim,
                                                const float* __restrict__ gamma_log,
                                                unsigned short* __restrict__ M16,
                                                const float* __restrict__ bin,
                                                float* __restrict__ biasc,
                                                const float* __restrict__ Cre,
                                                const float* __restrict__ Cim,
                                                unsigned short* __restrict__ C16) {
    __shared__ float Bs[16][17];
    __shared__ float Ws[16][17];
    const int blk = blockIdx.x;
    const int t = threadIdx.x;

    if (blk < PC_BASE) {
        // ---- prep_M: 32x32 grid of 16x16 tiles ----
        const int bx = blk & 31;
        const int by = blk >> 5;
        const int tx = t & 15;
        const int ty = t >> 4;
        const int j  = bx * 16 + tx;
        const int cc = by * 16 + ty;
        const float* Bsel = (cc < 256) ? (Bre + (size_t)cc * 512)
                                       : (Bim + (size_t)(cc - 256) * 512);
        float acc = 0.f;
        for (int kt = 0; kt < 512; kt += 16) {
            Bs[ty][tx] = Bsel[kt + tx];
            Ws[ty][tx] = W[(size_t)(kt + ty) * 512 + j];
            __syncthreads();
#pragma unroll
            for (int k = 0; k < 16; ++k) acc += Bs[ty][k] * Ws[k][tx];
            __syncthreads();
        }
        float g = expf(gamma_log[cc & 255]);
        M16[(size_t)cc * 512 + j] = f2bf(acc * g);
    } else if (blk < PB_BASE) {
        // ---- prep_C ----
        int idx = (blk - PC_BASE) * 256 + t;
        int o = idx >> 9;
        int s = idx & 511;
        float v = (s < 256) ? Cre[(size_t)o * 256 + s] : -Cim[(size_t)o * 256 + (s - 256)];
        C16[idx] = f2bf(v);
    } else if (blk < CVT_BASE) {
        // ---- prep_bias ----
        const int c = (blk - PB_BASE) * 4 + (t >> 6);
        const int lane = t & 63;
        const float* Bsel = (c < 256) ? (Bre + (size_t)c * 512)
                                      : (Bim + (size_t)(c - 256) * 512);
        float acc = 0.f;
#pragma unroll
        for (int i = lane; i < 512; i += 64) acc += bin[i] * Bsel[i];
#pragma unroll
        for (int off = 32; off > 0; off >>= 1) acc += __shfl_down(acc, off, 64);
        if (lane == 0) biasc[c] = acc * expf(gamma_log[c & 255]);
    } else {
        // ---- cvt f32 -> bf16: 16 loads pinned in flight (sched_barrier),
        // then 16 cvt+stores. VGPR must be >=64+overhead or the pin failed.
        const int i = (blk - CVT_BASE) * 256 + t;
        const float4* src = (const float4*)x;
        ushort4* dst = (ushort4*)x16;
        if (i < CVT_N4 - 15 * CVT_STR) {
            float4 v0  = src[i];
            float4 v1  = src[i +  1 * CVT_STR];
            float4 v2  = src[i +  2 * CVT_STR];
            float4 v3  = src[i +  3 * CVT_STR];
            float4 v4  = src[i +  4 * CVT_STR];
            float4 v5  = src[i +  5 * CVT_STR];
            float4 v6  = src[i +  6 * CVT_STR];
            float4 v7  = src[i +  7 * CVT_STR];
            float4 v8  = src[i +  8 * CVT_STR];
            float4 v9  = src[i +  9 * CVT_STR];
            float4 v10 = src[i + 10 * CVT_STR];
            float4 v11 = src[i + 11 * CVT_STR];
            float4 v12 = src[i + 12 * CVT_STR];
            float4 v13 = src[i + 13 * CVT_STR];
            float4 v14 = src[i + 14 * CVT_STR];
            float4 v15 = src[i + 15 * CVT_STR];
            __builtin_amdgcn_sched_barrier(0);   // pin: all 16 loads issue first
#define CVT1(K, V)                                                             \
            { ushort4 o; o.x = f2bf(V.x); o.y = f2bf(V.y);                     \
              o.z = f2bf(V.z); o.w = f2bf(V.w); dst[i + (K) * CVT_STR] = o; }
            CVT1(0, v0)  CVT1(1, v1)  CVT1(2, v2)  CVT1(3, v3)
            CVT1(4, v4)  CVT1(5, v5)  CVT1(6, v6)  CVT1(7, v7)
            CVT1(8, v8)  CVT1(9, v9)  CVT1(10, v10) CVT1(11, v11)
            CVT1(12, v12) CVT1(13, v13) CVT1(14, v14) CVT1(15, v15)
#undef CVT1
        } else {
#pragma unroll
            for (int k = 0; k < 16; ++k) {
                int idx = i + k * CVT_STR;
                if (idx < CVT_N4) {
                    float4 v = src[idx];
                    ushort4 o;
                    o.x = f2bf(v.x); o.y = f2bf(v.y); o.z = f2bf(v.z); o.w = f2bf(v.w);
                    dst[idx] = o;
                }
            }
        }
    }
}

// ---------------- bf16 MFMA GEMM: C = A @ B^T (+bias), K=N=512 ----------------
// Non-persistent, 2048 blocks (8 tiles/CU of work, 4 resident), 128x128 tile,
// 4 waves, BK=32 (16 K-iters), 2x16KB LDS buffers = 32KB -> with
// __launch_bounds__(256,4): 4 blocks/CU = 16 waves/CU (occupancy lever).
// Schedule = round-6/9: STAGE(next, buf^1) -> setprio + 16 MFMA -> syncthreads.
// LDS [row][slot] perm: read slot = ((lane>>4)+(row>>1))&3; stage source
// carries inverse kc = (slot-(row>>1))&3. 0 bank conflicts (r9 measured).
// XCD swizzle: xcd=bid&7; 4 col-siblings of a rowblk adjacent in dispatch.
template <bool OUT_BF16>
__global__ __launch_bounds__(256, 4) void gemm_mfma(const unsigned short* __restrict__ A,
                                                    const unsigned short* __restrict__ Bm,
                                                    const float* __restrict__ bias,
                                                    void* __restrict__ Cout,
                                                    int Mrows) {
    __shared__ __align__(16) unsigned short As[2][128 * 32];
    __shared__ __align__(16) unsigned short Bs[2][128 * 32];
    const int t = threadIdx.x;
    const int lane = t & 63;
    const int w = t >> 6;
    const int wr = (w >> 1) * 64;
    const int wc = (w & 1) * 64;
    const int bid = blockIdx.x;
    const int xcd = bid & 7;
    const int lid = bid >> 3;               // 0..255
    const int rowblk = xcd * 64 + (lid >> 2);
    const int colblk = lid & 3;
    const int row0 = rowblk * 128;
    const int col0 = colblk * 128;
    const int kt0  = (rowblk & 15) * 32;

    // per-thread stage geometry: chunks c_ = t and t+256; row=c_>>2, slot=c_&3
    const unsigned short* gaB[2];
    const unsigned short* gbB[2];
    int ldsoff[2];
#pragma unroll
    for (int qq = 0; qq < 2; ++qq) {
        int c_   = qq * 256 + t;           // 0..511
        int row_ = c_ >> 2;
        int sl_  = c_ & 3;
        int kc_  = (sl_ - (row_ >> 1)) & 3;   // inverse of read perm
        int ar_  = row0 + row_; if (ar_ >= Mrows) ar_ = Mrows - 1;
        gaB[qq] = A + (size_t)ar_ * KDIM + kc_ * 8;
        gbB[qq] = Bm + (size_t)(col0 + row_) * KDIM + kc_ * 8;
        ldsoff[qq] = c_ * 8;
    }

#define STAGE(pb, KT)                                                          \
    do {                                                                       \
        _Pragma("unroll")                                                      \
        for (int qq = 0; qq < 2; ++qq) {                                       \
            __builtin_amdgcn_global_load_lds(                                  \
                (const __attribute__((address_space(1))) unsigned int*)(gaB[qq] + (KT)), \
                (__attribute__((address_space(3))) unsigned int*)(&As[pb][ldsoff[qq]]), \
                16, 0, 0);                                                     \
            __builtin_amdgcn_global_load_lds(                                  \
                (const __attribute__((address_space(1))) unsigned int*)(gbB[qq] + (KT)), \
                (__attribute__((address_space(3))) unsigned int*)(&Bs[pb][ldsoff[qq]]), \
                16, 0, 0);                                                     \
        }                                                                      \
    } while (0)

    f32x4 acc[4][4] = {};

    STAGE(0, kt0);
    __syncthreads();                        // K-tile 0 resident

    int cur = 0;
    for (int it = 0; it < 16; ++it) {
        if (it < 15) STAGE(cur ^ 1, (kt0 + (it + 1) * 32) & 511);
        __builtin_amdgcn_s_setprio(1);
        {
            bf16x8 af[4], bfr[4];
#pragma unroll
            for (int i = 0; i < 4; ++i) {
                int row = wr + i * 16 + (lane & 15);
                int sa  = ((lane >> 4) + (row >> 1)) & 3;
                af[i] = *(const bf16x8*)(&As[cur][row * 32 + sa * 8]);
                int colr = wc + i * 16 + (lane & 15);
                int sb  = ((lane >> 4) + (colr >> 1)) & 3;
                bfr[i] = *(const bf16x8*)(&Bs[cur][colr * 32 + sb * 8]);
            }
#pragma unroll
            for (int i = 0; i < 4; ++i)
#pragma unroll
                for (int jj = 0; jj < 4; ++jj)
                    acc[i][jj] = __builtin_amdgcn_mfma_f32_16x16x32_bf16(
                        af[i], bfr[jj], acc[i][jj], 0, 0, 0);
        }
        __builtin_amdgcn_s_setprio(0);
        __syncthreads();    // publishes prefetched tile
        cur ^= 1;
    }
#undef STAGE

    // epilogue: C/D layout col=lane&15, row=(lane>>4)*4+reg  [m89/m91 verified]
    const int cq = lane >> 4;
    const int cl = lane & 15;
#pragma unroll
    for (int i = 0; i < 4; ++i) {
#pragma unroll
        for (int jj = 0; jj < 4; ++jj) {
#pragma unroll
            for (int r = 0; r < 4; ++r) {
                int grow = row0 + wr + i * 16 + cq * 4 + r;
                int gcol = col0 + wc + jj * 16 + cl;
                if (grow < Mrows) {
                    float v = acc[i][jj][r];
                    if (bias) v += bias[gcol];
                    if (OUT_BF16)
                        ((unsigned short*)Cout)[(size_t)grow * 512 + gcol] = f2bf(v);
                    else
                        ((float*)Cout)[(size_t)grow * 512 + gcol] = v;
                }
            }
        }
    }
}

// ---------------- tree recurrence, v2 (unchanged) ----------------
template <int E>
__global__ __launch_bounds__(256) void tree_up2(unsigned short* __restrict__ buf,
                                                const float* __restrict__ nu_log,
                                                const float* __restrict__ theta_log,
                                                int root_base, int nroots) {
    const int b = blockIdx.x;
    const int h = threadIdx.x >> 7;
    const int j2 = (threadIdx.x & 127) * 2;
    const int rr = blockIdx.y * 2 + h;
    if (rr >= nroots) return;
    const int rs = root_base + rr;
    constexpr int LEAVES = 1 << E;
    constexpr int NODES = LEAVES - 1;

    float lr0, li0, lr1, li1;
    { const float lam = expf(-expf(nu_log[j2]));     const float th = expf(theta_log[j2]);
      lr0 = lam * cosf(th); li0 = lam * sinf(th); }
    { const float lam = expf(-expf(nu_log[j2 + 1])); const float th = expf(theta_log[j2 + 1]);
      lr1 = lam * cosf(th); li1 = lam * sinf(th); }
    const size_t base = (size_t)b * 4095;

    unsigned int pr[LEAVES], pi[LEAVES];
    const int nbL = ((rs + 1) << E) - 1;
#pragma unroll
    for (int i = 0; i < LEAVES; ++i) {
        const size_t r = (base + nbL + i) * 512;
        pr[i] = *(const unsigned int*)(buf + r + j2);
        pi[i] = *(const unsigned int*)(buf + r + 256 + j2);
    }
    unsigned int qr[NODES], qi[NODES];
#pragma unroll
    for (int e = E - 1; e >= 0; --e) {
#pragma unroll
        for (int i = 0; i < (1 << e); ++i) {
            const int idx = LEAVES - (2 << e) + i;
            const size_t r = (base + (((rs + 1) << e) - 1) + i) * 512;
            qr[idx] = *(const unsigned int*)(buf + r + j2);
            qi[idx] = *(const unsigned int*)(buf + r + 256 + j2);
        }
    }
    __builtin_amdgcn_sched_barrier(0);

    float vr0[LEAVES], vi0[LEAVES], vr1[LEAVES], vi1[LEAVES];
#pragma unroll
    for (int i = 0; i < LEAVES; ++i) {
        vr0[i] = b2f_lo(pr[i]); vr1[i] = b2f_hi(pr[i]);
        vi0[i] = b2f_lo(pi[i]); vi1[i] = b2f_hi(pi[i]);
    }
#pragma unroll
    for (int e = E - 1; e >= 0; --e) {
#pragma unroll
        for (int i = 0; i < (1 << e); ++i) {
            const int idx = LEAVES - (2 << e) + i;
            const float cr0 = vr0[2 * i] + vr0[2 * i + 1];
            const float ci0 = vi0[2 * i] + vi0[2 * i + 1];
            const float cr1 = vr1[2 * i] + vr1[2 * i + 1];
            const float ci1 = vi1[2 * i] + vi1[2 * i + 1];
            const float hr0 = lr0 * cr0 - li0 * ci0 + b2f_lo(qr[idx]);
            const float hi0 = lr0 * ci0 + li0 * cr0 + b2f_lo(qi[idx]);
            const float hr1 = lr1 * cr1 - li1 * ci1 + b2f_hi(qr[idx]);
            const float hi1 = lr1 * ci1 + li1 * cr1 + b2f_hi(qi[idx]);
            const size_t r = (base + (((rs + 1) << e) - 1) + i) * 512;
            *(unsigned int*)(buf + r + j2) =
                (unsigned int)f2bf(hr0) | ((unsigned int)f2bf(hr1) << 16);
            *(unsigned int*)(buf + r + 256 + j2) =
                (unsigned int)f2bf(hi0) | ((unsigned int)f2bf(hi1) << 16);
            vr0[i] = hr0; vi0[i] = hi0; vr1[i] = hr1; vi1[i] = hi1;
        }
    }
}

extern "C" void kernel_launch(void* const* d_in, const int* in_sizes, int n_in,
                              void* d_out, int out_size, void* d_ws, size_t ws_size,
                              hipStream_t stream) {
    const float* x         = (const float*)d_in[0];
    const float* W_in      = (const float*)d_in[2];
    const float* b_in      = (const float*)d_in[3];
    const float* nu_log    = (const float*)d_in[4];
    const float* theta_log = (const float*)d_in[5];
    const float* gamma_log = (const float*)d_in[6];
    const float* B_re      = (const float*)d_in[7];
    const float* B_im      = (const float*)d_in[8];
    const float* C_re      = (const float*)d_in[9];
    const float* C_im      = (const float*)d_in[10];
    float* out = (float*)d_out;

    char* ws = (char*)d_ws;
    const size_t HB = (size_t)ROWS * 512 * 2;   // 67,092,480 bytes
    unsigned short* x16   = (unsigned short*)ws;
    unsigned short* hb16  = (unsigned short*)(ws + HB);
    unsigned short* M16   = (unsigned short*)(ws + 2 * HB);
    unsigned short* C16   = (unsigned short*)(ws + 2 * HB + 512 * 512 * 2);
    float*          biasc = (float*)(ws + 2 * HB + 2 * 512 * 512 * 2);

    prep_all<<<PREP_GRID, 256, 0, stream>>>(x, x16, W_in, B_re, B_im, gamma_log,
                                            M16, b_in, biasc, C_re, C_im, C16);

    gemm_mfma<true><<<2048, 256, 0, stream>>>(x16, M16, biasc, hb16, ROWS);

    tree_up2<4><<<dim3(16, 64), 256, 0, stream>>>(hb16, nu_log, theta_log, 127, 128);
    tree_up2<4><<<dim3(16, 4),  256, 0, stream>>>(hb16, nu_log, theta_log, 7, 8);
    tree_up2<3><<<dim3(16, 1),  256, 0, stream>>>(hb16, nu_log, theta_log, 0, 1);

    gemm_mfma<false><<<2048, 256, 0, stream>>>(hb16, C16, nullptr, out, ROWS);
}